// Round 10
// baseline (58.397 us; speedup 1.0000x reference)
//
#include <hip/hip_runtime.h>
#include <math.h>

#define B 64
#define N 16384
#define K 16
#define CHUNK 256                 // elements per wave-chunk
#define NCH   (N / CHUNK)         // 64 chunks per row
// ws float layout:
//   wV [B][NCH][K]  candidate values  @ 0       (65536 floats)
//   wI [B][NCH][K]  candidate indices @ 65536   (65536 ints)
//   wS [B][NCH]     chunk exp sums    @ 131072  (4096)
//   wM [B][NCH]     chunk max         @ 135168  (4096)
//   wC [B][48]      row consts        @ 139264  (c[16], idx[16] int, m0@32)
//   wE [B*N] bf16   E-cache           @ 143360  (1M ushorts = 2 MB)
#define WV_OFF 0
#define WI_OFF 65536
#define WS_OFF 131072
#define WM_OFF 135168
#define WC_OFF 139264
#define WE_OFF 143360

typedef float f4 __attribute__((ext_vector_type(4)));
typedef unsigned short u16x8 __attribute__((ext_vector_type(8)));

// monotone map fp32 -> uint32 (no NaNs in data)
__device__ __forceinline__ unsigned ordu(float x) {
  unsigned i = __float_as_uint(x);
  return (i & 0x80000000u) ? ~i : (i | 0x80000000u);
}
__device__ __forceinline__ int mbcnt64(unsigned long long m) {
  return __builtin_amdgcn_mbcnt_hi((unsigned)(m >> 32),
         __builtin_amdgcn_mbcnt_lo((unsigned)m, 0u));
}
// f32 -> bf16 RTNE (inputs are finite, in [0,1])
__device__ __forceinline__ unsigned short f2bf(float f) {
  unsigned b = __float_as_uint(f);
  b += 0x7FFFu + ((b >> 16) & 1u);
  return (unsigned short)(b >> 16);
}
__device__ __forceinline__ float bf2f(unsigned short v) {
  return __uint_as_float(((unsigned)v) << 16);
}

// ---------------- Kernel P: per-chunk top-16 + exp sum + E-cache + st ZERO-FILL ----------------
// 1024 blocks x 256 threads; wave = one 256-elem chunk. Zero-fills a contiguous
// 64 KB region of st per block with NONTEMPORAL stores (no L2 write-allocate);
// persists E = exp((x-mc)*1.5) as bf16 to ws.
__global__ __launch_bounds__(256)
void gtk_partial(const float* __restrict__ logits, const float* __restrict__ gumbel,
                 float* __restrict__ ws, float* __restrict__ st) {
  const int tid  = threadIdx.x;
  const int wave = tid >> 6, lane = tid & 63;
  const int gch  = blockIdx.x * 4 + wave;        // global chunk id (b*NCH + c)
  const int c    = gch & (NCH - 1);
  const size_t base = (size_t)gch * CHUNK;

  // slot-major layout: element e of lane = base + e*64 + lane (slot order == index order)
  float x[4]; unsigned u[4];
#pragma unroll
  for (int e = 0; e < 4; ++e) {
    const int o = e * 64 + lane;
    x[e] = logits[base + o] + gumbel[base + o];
    u[e] = ordu(x[e]);
  }

  // ---- st zero-fill: block owns st[blk*16384 .. +16384), NT stores ----
  {
    float* zst = st + ((size_t)blockIdx.x << 14);
    const f4 z = {0.f, 0.f, 0.f, 0.f};
#pragma unroll
    for (int i = 0; i < 16; ++i)
      __builtin_nontemporal_store(z, (f4*)(zst + i * 1024 + (tid << 2)));
  }

  // chunk max (butterfly)
  float mc = fmaxf(fmaxf(x[0], x[1]), fmaxf(x[2], x[3]));
#pragma unroll
  for (int off = 32; off; off >>= 1) mc = fmaxf(mc, __shfl_xor(mc, off));

  // E = exp((x-mc)*1.5): feed the chunk sum AND the bf16 E-cache
  unsigned short* wE = (unsigned short*)(ws + WE_OFF);
  float s = 0.f;
#pragma unroll
  for (int e = 0; e < 4; ++e) {
    const float Ee = __expf((x[e] - mc) * 1.5f);
    s += Ee;
    wE[base + e * 64 + lane] = f2bf(Ee);
  }
#pragma unroll
  for (int off = 32; off; off >>= 1) s += __shfl_xor(s, off);

  // radix bit-search: p = 16th largest orderable value in chunk
  unsigned p = 0;
#pragma unroll
  for (int bit = 31; bit >= 0; --bit) {
    const unsigned test = p | (1u << bit);
    int cnt = 0;
#pragma unroll
    for (int e = 0; e < 4; ++e) cnt += __popcll(__ballot(u[e] >= test));
    if (cnt >= K) p = test;
  }

  // extract top-16 set via ballot-prefix ranks (ties: smallest index first)
  unsigned long long bgt[4], beq[4];
#pragma unroll
  for (int e = 0; e < 4; ++e) { bgt[e] = __ballot(u[e] > p); beq[e] = __ballot(u[e] == p); }
  const int tg = __popcll(bgt[0]) + __popcll(bgt[1]) + __popcll(bgt[2]) + __popcll(bgt[3]);
  const int need = K - tg;
  float* wV = ws + WV_OFF + (size_t)gch * K;
  int*   wI = (int*)(ws + WI_OFF) + (size_t)gch * K;
  int gpre = 0, epre = 0;
#pragma unroll
  for (int e = 0; e < 4; ++e) {
    const int myi = (c << 8) + e * 64 + lane;     // row-local index
    if (u[e] > p) {
      const int r = gpre + mbcnt64(bgt[e]);
      wV[r] = x[e]; wI[r] = myi;
    } else if (u[e] == p) {
      const int r = epre + mbcnt64(beq[e]);
      if (r < need) { wV[tg + r] = x[e]; wI[tg + r] = myi; }
    }
    gpre += __popcll(bgt[e]); epre += __popcll(beq[e]);
  }

  if (lane == 0) {
    (ws + WS_OFF)[gch] = s;
    (ws + WM_OFF)[gch] = mc;
  }
}

// ---------------- Kernel M: per-row merge -> constants + st one-hot scatter ----------------
// 64 blocks x 256 threads. Wave-level radix-select -> 64 survivors -> wave-0
// radix-select -> exact rank-sort of final 16 -> c_k, idx, m0; scatter 16 ones.
__global__ __launch_bounds__(256)
void gtk_merge(float* __restrict__ ws, float* __restrict__ st) {
  const int b = blockIdx.x;
  const int tid = threadIdx.x, wave = tid >> 6, lane = tid & 63;

  __shared__ float lv[64];
  __shared__ int   li[64];
  __shared__ float tv[K];
  __shared__ int   ti[K];
  __shared__ float sv16[K];
  __shared__ int   si16[K];

  const float* wV = ws + WV_OFF + (size_t)b * (NCH * K);
  const int*   wI = (const int*)(ws + WI_OFF) + (size_t)b * (NCH * K);

  float xv[4]; unsigned xu[4]; int xi[4];
#pragma unroll
  for (int e = 0; e < 4; ++e) {
    const int q = wave * 256 + e * 64 + lane;
    xv[e] = wV[q]; xi[e] = wI[q]; xu[e] = ordu(xv[e]);
  }

  unsigned p = 0;
#pragma unroll
  for (int bit = 31; bit >= 0; --bit) {
    const unsigned test = p | (1u << bit);
    int cnt = 0;
#pragma unroll
    for (int e = 0; e < 4; ++e) cnt += __popcll(__ballot(xu[e] >= test));
    if (cnt >= K) p = test;
  }
  unsigned long long bgt[4], beq[4];
#pragma unroll
  for (int e = 0; e < 4; ++e) { bgt[e] = __ballot(xu[e] > p); beq[e] = __ballot(xu[e] == p); }
  const int tg = __popcll(bgt[0]) + __popcll(bgt[1]) + __popcll(bgt[2]) + __popcll(bgt[3]);
  const int need = K - tg;
  int gpre = 0, epre = 0;
#pragma unroll
  for (int e = 0; e < 4; ++e) {
    if (xu[e] > p) {
      const int r = gpre + mbcnt64(bgt[e]);
      lv[wave * K + r] = xv[e]; li[wave * K + r] = xi[e];
    } else if (xu[e] == p) {
      const int r = epre + mbcnt64(beq[e]);
      if (r < need) { lv[wave * K + tg + r] = xv[e]; li[wave * K + tg + r] = xi[e]; }
    }
    gpre += __popcll(bgt[e]); epre += __popcll(beq[e]);
  }
  __syncthreads();

  if (wave == 0) {
    const float v = lv[lane]; const int i = li[lane];
    const unsigned uu = ordu(v);
    unsigned p2 = 0;
#pragma unroll
    for (int bit = 31; bit >= 0; --bit) {
      const unsigned test = p2 | (1u << bit);
      if (__popcll(__ballot(uu >= test)) >= K) p2 = test;
    }
    const unsigned long long g = __ballot(uu > p2);
    const unsigned long long q = __ballot(uu == p2);
    const int tg2 = __popcll(g), nd2 = K - tg2;
    if (uu > p2) {
      const int r = mbcnt64(g);
      tv[r] = v; ti[r] = i;
    } else if (uu == p2) {
      const int r = mbcnt64(q);
      if (r < nd2) { tv[tg2 + r] = v; ti[tg2 + r] = i; }
    }
    // exact order: rank by (value desc, original index asc)
    if (lane < K) {
      const float mv = tv[lane]; const int mi = ti[lane];
      int rk = 0;
#pragma unroll
      for (int j = 0; j < K; ++j) {
        const float ov = tv[j]; const int oi = ti[j];
        rk += (ov > mv || (ov == mv && oi < mi)) ? 1 : 0;
      }
      sv16[rk] = mv; si16[rk] = mi;
    }
    const float m0 = sv16[0];

    // A_all from chunk sums (NCH == 64 == wave width)
    const float S   = (ws + WS_OFF)[b * NCH + lane];
    const float mcc = (ws + WM_OFF)[b * NCH + lane];
    float a = S * __expf((mcc - m0) * 1.5f);
#pragma unroll
    for (int off = 32; off; off >>= 1) a += __shfl_xor(a, off);

    if (lane == 0) {
      float* wrow = ws + WC_OFF + (size_t)b * 48;
      float D = a;                                  // D_k = A_all - sum_{j<k} e_j
#pragma unroll
      for (int j = 0; j < K; ++j) {
        wrow[j] = 1.0f / D;
        D -= __expf((sv16[j] - m0) * 1.5f);
      }
      int* wi = (int*)(wrow + K);
#pragma unroll
      for (int j = 0; j < K; ++j) wi[j] = si16[j];
      wrow[32] = m0;
    }

    // scatter the one-hot 1s into st (P already zero-filled it)
    if (lane < K) {
      st[(size_t)lane * (size_t)(B * N) + (size_t)b * N + si16[lane]] = 1.0f;
    }
  }
}

// ---------------- Kernel S: softs from the 2.1 MB bf16 E-cache, NT stores ----------------
// 2048 blocks x 256 threads. Block = one 8192-elem (32 KB) contiguous run of ONE
// softs plane; reads 16 KB of E (cache-resident by size), rescales by the
// per-chunk factor exp((mc-m0)*1.5)*c_k, NONTEMPORAL float4 store walk.
// Selected-position zeroing: post-loop same-thread fix-up after vmcnt(0).
__global__ __launch_bounds__(256)
void gtk_soft(const float* __restrict__ ws, float* __restrict__ softs) {
  const int bid = blockIdx.x, tid = threadIdx.x;
  const int xcd = bid & 7;
  const int j   = bid >> 3;
  const int k   = j & 15;
  const int s8  = j >> 4;               // [0,16)
  const int seg = s8 * 8 + xcd;         // [0,128)
  const int b   = seg >> 1;
  const int n0  = (seg & 1) << 13;      // 8192-elem half-row
  const size_t base = (size_t)b * N + n0;

  __shared__ float ssc[32];             // per-local-chunk scale = exp((mc-m0)*1.5)*ck
  __shared__ int   sidx[K];
  const float* wrow = ws + WC_OFF + (size_t)b * 48;
  if (tid < K) sidx[tid] = ((const int*)(wrow + K))[tid];
  if (tid < 32) {
    const float m0  = wrow[32];
    const float ck  = wrow[k];
    const float mcc = (ws + WM_OFF)[b * NCH + (n0 >> 8) + tid];
    ssc[tid] = __expf((mcc - m0) * 1.5f) * ck;
  }
  __syncthreads();

  const unsigned short* Eb = (const unsigned short*)(ws + WE_OFF) + base;
  float* dst = softs + (size_t)k * (size_t)(B * N) + base;

#pragma unroll
  for (int i = 0; i < 4; ++i) {
    const int off = i * 2048 + (tid << 3);          // 8 elems/thread/iter
    const u16x8 ev = *(const u16x8*)(Eb + off);
    const float sc = ssc[i * 8 + (tid >> 5)];       // 8 consecutive elems: one chunk
    f4 s0, s1;
#pragma unroll
    for (int e = 0; e < 4; ++e) {
      s0[e] = bf2f(ev[e])     * sc;
      s1[e] = bf2f(ev[4 + e]) * sc;
    }
    __builtin_nontemporal_store(s0, (f4*)(dst + off));
    __builtin_nontemporal_store(s1, (f4*)(dst + off + 4));
  }

  // fix-up: zero positions selected before step k; same thread that stored them.
  // Drain outstanding NT stores first so the zero is last-writer at that address.
  asm volatile("s_waitcnt vmcnt(0)" ::: "memory");
#pragma unroll
  for (int jj = 0; jj < K; ++jj) {
    const int d = sidx[jj] - n0;
    if ((jj < k) && ((unsigned)d < 8192u) && (((d & 2047) >> 3) == tid))
      __builtin_nontemporal_store(0.f, dst + d);
  }
}

extern "C" void kernel_launch(void* const* d_in, const int* in_sizes, int n_in,
                              void* d_out, int out_size, void* d_ws, size_t ws_size,
                              hipStream_t stream) {
  const float* logits = (const float*)d_in[0];
  const float* gumbel = (const float*)d_in[1];
  float* st    = (float*)d_out;                      // [K,B,N]
  float* softs = st + (size_t)K * B * N;             // [K,B,N]
  float* ws    = (float*)d_ws;

  gtk_partial<<<(B * NCH) / 4, 256, 0, stream>>>(logits, gumbel, ws, st);
  gtk_merge<<<B, 256, 0, stream>>>(ws, st);
  gtk_soft<<<2048, 256, 0, stream>>>(ws, softs);
}

// Round 13
// 42.183 us; speedup vs baseline: 1.3844x; 1.3844x over previous
//
#include <hip/hip_runtime.h>
#include <math.h>

#define B 64
#define N 16384
#define K 16
#define CHUNK 256                 // elements per wave-chunk
#define NCH   (N / CHUNK)         // 64 chunks per row
// ws float layout:
//   wV   [B][NCH][K]  candidate values  @ 0       (65536 floats)  -- dead after M reads it;
//   sct  [B][NCH][K]  scale table       @ 0       (65536 floats)  -- M overwrites row-local
//   wI   [B][NCH][K]  candidate indices @ 65536   (65536 ints)
//   wS   [B][NCH]     chunk exp sums    @ 131072  (4096)
//   wM   [B][NCH]     chunk max         @ 135168  (4096)
//   wC   [B][48]      row consts        @ 139264  (c[16], idx[16] int, m0@32)
//   wE   [B*N] bf16   E-cache           @ 142336  (1M ushorts = 2 MB)
#define WV_OFF 0
#define SCT_OFF 0
#define WI_OFF 65536
#define WS_OFF 131072
#define WM_OFF 135168
#define WC_OFF 139264
#define WE_OFF 142336

typedef float f4 __attribute__((ext_vector_type(4)));
typedef unsigned short u16x4 __attribute__((ext_vector_type(4)));

// monotone map fp32 -> uint32 (no NaNs in data)
__device__ __forceinline__ unsigned ordu(float x) {
  unsigned i = __float_as_uint(x);
  return (i & 0x80000000u) ? ~i : (i | 0x80000000u);
}
__device__ __forceinline__ int mbcnt64(unsigned long long m) {
  return __builtin_amdgcn_mbcnt_hi((unsigned)(m >> 32),
         __builtin_amdgcn_mbcnt_lo((unsigned)m, 0u));
}
// f32 -> bf16 RTNE (inputs are finite, in [0,1])
__device__ __forceinline__ unsigned short f2bf(float f) {
  unsigned b = __float_as_uint(f);
  b += 0x7FFFu + ((b >> 16) & 1u);
  return (unsigned short)(b >> 16);
}
__device__ __forceinline__ float bf2f(unsigned short v) {
  return __uint_as_float(((unsigned)v) << 16);
}

// ---------------- Kernel P: per-chunk top-16 + exp sum + E-cache (compute-only) ----------------
// 1024 blocks x 256 threads; wave = one 256-elem chunk.
__global__ __launch_bounds__(256)
void gtk_partial(const float* __restrict__ logits, const float* __restrict__ gumbel,
                 float* __restrict__ ws) {
  const int tid  = threadIdx.x;
  const int wave = tid >> 6, lane = tid & 63;
  const int gch  = blockIdx.x * 4 + wave;        // global chunk id (b*NCH + c)
  const int c    = gch & (NCH - 1);
  const size_t base = (size_t)gch * CHUNK;

  // slot-major: element e of lane = base + e*64 + lane (slot order == index order)
  float x[4]; unsigned u[4];
#pragma unroll
  for (int e = 0; e < 4; ++e) {
    const int o = e * 64 + lane;
    x[e] = logits[base + o] + gumbel[base + o];
    u[e] = ordu(x[e]);
  }

  // chunk max (butterfly)
  float mc = fmaxf(fmaxf(x[0], x[1]), fmaxf(x[2], x[3]));
#pragma unroll
  for (int off = 32; off; off >>= 1) mc = fmaxf(mc, __shfl_xor(mc, off));

  // E = exp((x-mc)*1.5): chunk sum + bf16 E-cache
  unsigned short* wE = (unsigned short*)(ws + WE_OFF);
  float s = 0.f;
#pragma unroll
  for (int e = 0; e < 4; ++e) {
    const float Ee = __expf((x[e] - mc) * 1.5f);
    s += Ee;
    wE[base + e * 64 + lane] = f2bf(Ee);
  }
#pragma unroll
  for (int off = 32; off; off >>= 1) s += __shfl_xor(s, off);

  // radix bit-search: p = 16th largest orderable value in chunk
  unsigned p = 0;
#pragma unroll
  for (int bit = 31; bit >= 0; --bit) {
    const unsigned test = p | (1u << bit);
    int cnt = 0;
#pragma unroll
    for (int e = 0; e < 4; ++e) cnt += __popcll(__ballot(u[e] >= test));
    if (cnt >= K) p = test;
  }

  // extract top-16 set via ballot-prefix ranks (ties: smallest index first)
  unsigned long long bgt[4], beq[4];
#pragma unroll
  for (int e = 0; e < 4; ++e) { bgt[e] = __ballot(u[e] > p); beq[e] = __ballot(u[e] == p); }
  const int tg = __popcll(bgt[0]) + __popcll(bgt[1]) + __popcll(bgt[2]) + __popcll(bgt[3]);
  const int need = K - tg;
  float* wV = ws + WV_OFF + (size_t)gch * K;
  int*   wI = (int*)(ws + WI_OFF) + (size_t)gch * K;
  int gpre = 0, epre = 0;
#pragma unroll
  for (int e = 0; e < 4; ++e) {
    const int myi = (c << 8) + e * 64 + lane;     // row-local index
    if (u[e] > p) {
      const int r = gpre + mbcnt64(bgt[e]);
      wV[r] = x[e]; wI[r] = myi;
    } else if (u[e] == p) {
      const int r = epre + mbcnt64(beq[e]);
      if (r < need) { wV[tg + r] = x[e]; wI[tg + r] = myi; }
    }
    gpre += __popcll(bgt[e]); epre += __popcll(beq[e]);
  }

  if (lane == 0) {
    (ws + WS_OFF)[gch] = s;
    (ws + WM_OFF)[gch] = mc;
  }
}

// ---------------- Kernel M: per-row merge -> constants + scale table ----------------
// 64 blocks x 256 threads. Radix-select to top-16, exact rank-sort, c_k/idx/m0,
// then all 256 threads build sct[b][c][k] = exp((mc-m0)*1.5)*c_k (overwrites wV,
// which this block has fully consumed; rows are block-disjoint).
__global__ __launch_bounds__(256)
void gtk_merge(float* __restrict__ ws) {
  const int b = blockIdx.x;
  const int tid = threadIdx.x, wave = tid >> 6, lane = tid & 63;

  __shared__ float lv[64];
  __shared__ int   li[64];
  __shared__ float tv[K];
  __shared__ int   ti[K];
  __shared__ float sv16[K];
  __shared__ int   si16[K];
  __shared__ float scg[K];

  const float* rV = ws + WV_OFF + (size_t)b * (NCH * K);
  const int*   rI = (const int*)(ws + WI_OFF) + (size_t)b * (NCH * K);

  float xv[4]; unsigned xu[4]; int xi[4];
#pragma unroll
  for (int e = 0; e < 4; ++e) {
    const int q = wave * 256 + e * 64 + lane;
    xv[e] = rV[q]; xi[e] = rI[q]; xu[e] = ordu(xv[e]);
  }

  unsigned p = 0;
#pragma unroll
  for (int bit = 31; bit >= 0; --bit) {
    const unsigned test = p | (1u << bit);
    int cnt = 0;
#pragma unroll
    for (int e = 0; e < 4; ++e) cnt += __popcll(__ballot(xu[e] >= test));
    if (cnt >= K) p = test;
  }
  unsigned long long bgt[4], beq[4];
#pragma unroll
  for (int e = 0; e < 4; ++e) { bgt[e] = __ballot(xu[e] > p); beq[e] = __ballot(xu[e] == p); }
  const int tg = __popcll(bgt[0]) + __popcll(bgt[1]) + __popcll(bgt[2]) + __popcll(bgt[3]);
  const int need = K - tg;
  int gpre = 0, epre = 0;
#pragma unroll
  for (int e = 0; e < 4; ++e) {
    if (xu[e] > p) {
      const int r = gpre + mbcnt64(bgt[e]);
      lv[wave * K + r] = xv[e]; li[wave * K + r] = xi[e];
    } else if (xu[e] == p) {
      const int r = epre + mbcnt64(beq[e]);
      if (r < need) { lv[wave * K + tg + r] = xv[e]; li[wave * K + tg + r] = xi[e]; }
    }
    gpre += __popcll(bgt[e]); epre += __popcll(beq[e]);
  }
  __syncthreads();

  if (wave == 0) {
    const float v = lv[lane]; const int i = li[lane];
    const unsigned uu = ordu(v);
    unsigned p2 = 0;
#pragma unroll
    for (int bit = 31; bit >= 0; --bit) {
      const unsigned test = p2 | (1u << bit);
      if (__popcll(__ballot(uu >= test)) >= K) p2 = test;
    }
    const unsigned long long g = __ballot(uu > p2);
    const unsigned long long q = __ballot(uu == p2);
    const int tg2 = __popcll(g), nd2 = K - tg2;
    if (uu > p2) {
      const int r = mbcnt64(g);
      tv[r] = v; ti[r] = i;
    } else if (uu == p2) {
      const int r = mbcnt64(q);
      if (r < nd2) { tv[tg2 + r] = v; ti[tg2 + r] = i; }
    }
    // exact order: rank by (value desc, original index asc)
    if (lane < K) {
      const float mv = tv[lane]; const int mi = ti[lane];
      int rk = 0;
#pragma unroll
      for (int j = 0; j < K; ++j) {
        const float ov = tv[j]; const int oi = ti[j];
        rk += (ov > mv || (ov == mv && oi < mi)) ? 1 : 0;
      }
      sv16[rk] = mv; si16[rk] = mi;
    }
    const float m0 = sv16[0];

    // A_all from chunk sums (NCH == 64 == wave width)
    const float S   = (ws + WS_OFF)[b * NCH + lane];
    const float mcc = (ws + WM_OFF)[b * NCH + lane];
    float a = S * __expf((mcc - m0) * 1.5f);
#pragma unroll
    for (int off = 32; off; off >>= 1) a += __shfl_xor(a, off);

    if (lane == 0) {
      float* wrow = ws + WC_OFF + (size_t)b * 48;
      float D = a;                                  // D_k = A_all - sum_{j<k} e_j
#pragma unroll
      for (int j = 0; j < K; ++j) {
        const float cj = 1.0f / D;
        wrow[j] = cj;
        scg[j]  = cj;
        D -= __expf((sv16[j] - m0) * 1.5f);
      }
      int* wi = (int*)(wrow + K);
#pragma unroll
      for (int j = 0; j < K; ++j) wi[j] = si16[j];
      wrow[32] = m0;
    }
  }
  __syncthreads();

  // ---- scale table: sct[b][c][k] = exp((mc[c]-m0)*1.5) * c_k ----
  const float m0 = sv16[0];
  float* sct = ws + SCT_OFF + (size_t)b * (NCH * K);
#pragma unroll
  for (int e = 0; e < 4; ++e) {
    const int idx = tid + (e << 8);               // [0,1024)
    const int c   = idx >> 4, kk = idx & 15;
    const float mcc = (ws + WM_OFF)[b * NCH + c];
    sct[idx] = __expf((mcc - m0) * 1.5f) * scg[kk];
  }
}

// ---------------- Kernel O: fillBuffer-style monotone sweep of ALL outputs ----------------
// 1024 blocks x 256 threads, grid-stride with window = 1M elems (4 MB): the whole
// grid writes one contiguous plane window per iteration, marching linearly
// through d_out (16 st zero-planes, then 16 softs planes). Each thread's E slice
// and scale cacheline are iteration-invariant -> registers/L1. No fix-ups here.
__global__ __launch_bounds__(256)
void gtk_sweep(const float* __restrict__ ws, float* __restrict__ out) {
  const int lin = (blockIdx.x << 8) + threadIdx.x;   // [0, 262144)
  const size_t g0 = (size_t)lin << 2;                // elem offset within a plane

  // phase 1: st = zeros, 16 compact windows in address order
  const f4 z = {0.f, 0.f, 0.f, 0.f};
#pragma unroll 1
  for (int it = 0; it < 16; ++it)
    *(f4*)(out + (size_t)it * 1048576 + g0) = z;

  // phase 2: softs = E * sct[c][k], 16 compact windows in address order
  const int elem  = lin << 2;                        // [0, 1M)
  const int cglob = elem >> 8;                       // b*64+c
  const u16x4 ev = *(const u16x4*)((const unsigned short*)(ws + WE_OFF) + elem);
  const float e0 = bf2f(ev[0]), e1 = bf2f(ev[1]), e2 = bf2f(ev[2]), e3 = bf2f(ev[3]);
  const float* sct = ws + SCT_OFF + ((size_t)cglob << 4);
  float* sfp = out + 16777216;
#pragma unroll 1
  for (int k = 0; k < 16; ++k) {
    const float sc = sct[k];                         // same 64B line all 16 iters
    f4 s = {e0 * sc, e1 * sc, e2 * sc, e3 * sc};
    *(f4*)(sfp + (size_t)k * 1048576 + g0) = s;
  }
}

// ---------------- Kernel F: scattered fix-ups AFTER the sweep ----------------
// 64 blocks x 256 threads (one block per row). st: 16 ones. softs: zero the
// positions selected before step k (120 per row). Kernel boundary orders these
// after O's tile stores.
__global__ __launch_bounds__(256)
void gtk_fix(const float* __restrict__ ws, float* __restrict__ st,
             float* __restrict__ softs) {
  const int b = blockIdx.x, tid = threadIdx.x;
  __shared__ int sidx[K];
  if (tid < K) sidx[tid] = ((const int*)(ws + WC_OFF + (size_t)b * 48 + K))[tid];
  __syncthreads();
  const size_t plane = 1048576, rowb = (size_t)b * N;
  if (tid < K) st[(size_t)tid * plane + rowb + sidx[tid]] = 1.0f;
  const int k = tid >> 4, j = tid & 15;
  if (j < k) softs[(size_t)k * plane + rowb + sidx[j]] = 0.0f;
}

extern "C" void kernel_launch(void* const* d_in, const int* in_sizes, int n_in,
                              void* d_out, int out_size, void* d_ws, size_t ws_size,
                              hipStream_t stream) {
  const float* logits = (const float*)d_in[0];
  const float* gumbel = (const float*)d_in[1];
  float* st    = (float*)d_out;                      // [K,B,N]
  float* softs = st + (size_t)K * B * N;             // [K,B,N]
  float* ws    = (float*)d_ws;

  gtk_partial<<<(B * NCH) / 4, 256, 0, stream>>>(logits, gumbel, ws);
  gtk_merge<<<B, 256, 0, stream>>>(ws);
  gtk_sweep<<<1024, 256, 0, stream>>>(ws, (float*)d_out);
  gtk_fix<<<B, 256, 0, stream>>>(ws, st, softs);
}